// Round 1
// baseline (272.344 us; speedup 1.0000x reference)
//
#include <hip/hip_runtime.h>
#include <hip/hip_bf16.h>

#define NF   1024   // N features
#define NHID 256    // H hidden
#define NJ   1280   // N+H keys
#define ED   64     // E = HD = 64
#define BATCH 8192

__device__ __forceinline__ float fast_tanh(float x) {
    // tanh(x) = (e^{2x}-1)/(e^{2x}+1); exact identity, __expf ~2ulp, rcp ~1ulp
    float e = __expf(2.0f * x);
    float r = __builtin_amdgcn_rcpf(e + 1.0f);
    return (e - 1.0f) * r;
}

// ---------------- Kernel 1: BvT[e][j] = (full @ W2)[j][e] + b_w[e] ----------------
__global__ __launch_bounds__(256) void prep_bvt_kernel(
    const float* __restrict__ feat, const float* __restrict__ hid,
    const float* __restrict__ Ww, const float* __restrict__ bw,
    float* __restrict__ BvT)
{
    __shared__ float rows_s[64][64];
    __shared__ float W2_s[64][64];
    const int j0  = blockIdx.x * 64;
    const int tid = threadIdx.x;

    for (int t = tid; t < 64 * 64; t += 256)
        W2_s[t >> 6][t & 63] = Ww[64 * 64 + t];          // W2 = rows 64..127 of W_w
    for (int t = tid; t < 64 * 64; t += 256) {
        int jl = t >> 6, k = t & 63;
        int j = j0 + jl;
        rows_s[jl][k] = (j < NF) ? feat[(size_t)j * 64 + k]
                                 : hid[(size_t)(j - NF) * 64 + k];
    }
    __syncthreads();

    const int e  = tid & 63;
    const int jg = tid >> 6;     // 0..3, 16 rows each
    float acc[16];
    #pragma unroll
    for (int r = 0; r < 16; r++) acc[r] = 0.f;
    for (int k = 0; k < 64; k++) {
        float w = W2_s[k][e];
        #pragma unroll
        for (int r = 0; r < 16; r++)
            acc[r] += rows_s[jg * 16 + r][k] * w;
    }
    const float bwe = bw[e];
    #pragma unroll
    for (int r = 0; r < 16; r++) {
        int j = j0 + jg * 16 + r;
        BvT[(size_t)e * NJ + j] = acc[r] + bwe;          // transposed store (scattered, tiny)
    }
}

// ------------- Kernel 2: fused score / masked exp / rowsum / context (2 rows/block) -------------
__global__ __launch_bounds__(256) void score_ctx_kernel(
    const float* __restrict__ feat, const float* __restrict__ hid,
    const float* __restrict__ Ww, const float* __restrict__ Wu,
    const float* __restrict__ BvT, const void* __restrict__ maskp,
    float* __restrict__ ctx)
{
    __shared__ float sA[2][ED];
    __shared__ float sWu[ED];
    __shared__ float sc[2][NJ];
    __shared__ float red[2][4][ED];
    __shared__ float ssum[2];
    __shared__ float wpart[2][4];
    __shared__ int   mtype_s;

    const int tid = threadIdx.x;
    const int i0  = blockIdx.x * 2;

    // --- detect mask encoding (uint8 / int32 / float32) from first 64 words ---
    if (tid < 64) {
        const unsigned int* mw = (const unsigned int*)maskp;
        unsigned int w = mw[tid];
        unsigned long long notf = __ballot(w != 0u && w != 0x3F800000u);
        unsigned long long gt1  = __ballot(w > 1u);
        if (tid == 0) {
            int mt;
            if (notf == 0ull)     mt = 2;   // float32 pattern {0, 1.0f}
            else if (gt1 == 0ull) mt = 1;   // int32 {0,1}
            else                  mt = 0;   // uint8 packed
            mtype_s = mt;
        }
        sWu[tid] = Wu[tid];
    }
    // --- compute A rows for i0, i0+1 in-block: A_i[e] = feat[i]·W1[:,e] ---
    if (tid < 128) {
        int half = tid >> 6, e = tid & 63;
        const float* frow = feat + (size_t)(i0 + half) * ED;
        float a = 0.f;
        #pragma unroll
        for (int k = 0; k < ED; k++) a += frow[k] * Ww[k * ED + e];  // W1 = rows 0..63
        sA[half][e] = a;
    }
    __syncthreads();

    const int mtype = mtype_s;
    const unsigned char* m8  = (const unsigned char*)maskp;
    const unsigned int*  m32 = (const unsigned int*)maskp;
    const float*         mfl = (const float*)maskp;

    // --- phase 1: scores for both rows ---
    float lsum0 = 0.f, lsum1 = 0.f;
    for (int jj = 0; jj < NJ / 256; jj++) {
        const int j = jj * 256 + tid;
        float s0 = 0.f, s1 = 0.f;
        for (int e = 0; e < ED; e++) {
            float bv = BvT[(size_t)e * NJ + j];   // coalesced across lanes
            float wu = sWu[e];
            s0 += wu * fast_tanh(sA[0][e] + bv);
            s1 += wu * fast_tanh(sA[1][e] + bv);
        }
        size_t off0 = (size_t)i0 * NJ + j, off1 = off0 + NJ;
        bool b0, b1;
        if (mtype == 0)      { b0 = m8[off0]  != 0;   b1 = m8[off1]  != 0;   }
        else if (mtype == 1) { b0 = m32[off0] != 0u;  b1 = m32[off1] != 0u;  }
        else                 { b0 = mfl[off0] != 0.f; b1 = mfl[off1] != 0.f; }
        float e0 = b0 ? __expf(s0) : 0.f;
        float e1 = b1 ? __expf(s1) : 0.f;
        sc[0][j] = e0; sc[1][j] = e1;
        lsum0 += e0;  lsum1 += e1;
    }
    // --- row-sum reduction (wave shuffle + LDS across 4 waves) ---
    #pragma unroll
    for (int off = 32; off > 0; off >>= 1) {
        lsum0 += __shfl_down(lsum0, off);
        lsum1 += __shfl_down(lsum1, off);
    }
    if ((tid & 63) == 0) { wpart[0][tid >> 6] = lsum0; wpart[1][tid >> 6] = lsum1; }
    __syncthreads();
    if (tid < 2) {
        float s = wpart[tid][0] + wpart[tid][1] + wpart[tid][2] + wpart[tid][3];
        ssum[tid] = (s == 0.f) ? 1.f : s;
    }
    __syncthreads();

    // --- phase 2: context_un[i][e] = sum_j sc[i][j]*full[j][e] ---
    const int e  = tid & 63;
    const int jg = tid >> 6;   // wave-uniform
    float a0 = 0.f, a1 = 0.f;
    for (int j = jg; j < NJ; j += 4) {
        const float* fr = (j < NF) ? (feat + (size_t)j * ED)
                                   : (hid  + (size_t)(j - NF) * ED);
        float f = fr[e];                        // coalesced across lanes
        a0 += sc[0][j] * f;                     // sc broadcast (j uniform per wave)
        a1 += sc[1][j] * f;
    }
    red[0][jg][e] = a0;
    red[1][jg][e] = a1;
    __syncthreads();
    if (tid < 128) {
        int half = tid >> 6, ee = tid & 63;
        float v = red[half][0][ee] + red[half][1][ee] + red[half][2][ee] + red[half][3][ee];
        ctx[(size_t)(i0 + half) * ED + ee] = v / ssum[half];
    }
}

// ---------------- Kernel 3: out = values(8192x1024) @ ctx(1024x64), fp32 tiled ----------------
__global__ __launch_bounds__(256) void out_mm_kernel(
    const float* __restrict__ values, const float* __restrict__ ctx,
    float* __restrict__ out)
{
    __shared__ float vs[32][64];   // values tile: 32 rows x 64 k
    __shared__ float cs[64][64];   // ctx tile:    64 k x 64 e
    const int r0   = blockIdx.x * 32;
    const int tid  = threadIdx.x;
    const int lane = tid & 63;
    const int wave = tid >> 6;
    const int e2   = (lane & 31) * 2;            // 2 cols per thread
    const int rg   = wave * 2 + (lane >> 5);     // 0..7, 4 rows per thread

    float acc[4][2];
    #pragma unroll
    for (int r = 0; r < 4; r++) { acc[r][0] = 0.f; acc[r][1] = 0.f; }

    for (int k0 = 0; k0 < NF; k0 += 64) {
        __syncthreads();
        // stage values 32x64 (512 float4, 2/thread)
        for (int t = tid; t < 512; t += 256) {
            int r = t >> 4, c4 = t & 15;
            *(float4*)&vs[r][c4 * 4] =
                *(const float4*)&values[(size_t)(r0 + r) * NF + k0 + c4 * 4];
        }
        // stage ctx 64x64 (1024 float4, 4/thread)
        for (int t = tid; t < 1024; t += 256) {
            int kk = t >> 4, c4 = t & 15;
            *(float4*)&cs[kk][c4 * 4] =
                *(const float4*)&ctx[(size_t)(k0 + kk) * ED + c4 * 4];
        }
        __syncthreads();
        for (int k = 0; k < 64; k += 2) {
            float2 ca = *(const float2*)&cs[k][e2];
            float2 cb = *(const float2*)&cs[k + 1][e2];
            #pragma unroll
            for (int rr = 0; rr < 4; rr++) {
                float2 v = *(const float2*)&vs[rg * 4 + rr][k];  // broadcast read
                acc[rr][0] += v.x * ca.x + v.y * cb.x;
                acc[rr][1] += v.x * ca.y + v.y * cb.y;
            }
        }
    }
    #pragma unroll
    for (int rr = 0; rr < 4; rr++) {
        int r = r0 + rg * 4 + rr;
        *(float2*)&out[(size_t)r * ED + e2] = make_float2(acc[rr][0], acc[rr][1]);
    }
}

extern "C" void kernel_launch(void* const* d_in, const int* in_sizes, int n_in,
                              void* d_out, int out_size, void* d_ws, size_t ws_size,
                              hipStream_t stream) {
    const float* values = (const float*)d_in[0];
    const float* feat   = (const float*)d_in[1];
    const float* hid    = (const float*)d_in[2];
    const float* Ww     = (const float*)d_in[3];
    const float* bw     = (const float*)d_in[4];
    const float* Wu     = (const float*)d_in[5];
    const void*  mask   = d_in[6];
    float* out = (float*)d_out;

    float* BvT = (float*)d_ws;                                   // 64*1280*4 = 320 KiB
    float* ctx = (float*)((char*)d_ws + (size_t)ED * NJ * 4);    // 1024*64*4 = 256 KiB

    hipLaunchKernelGGL(prep_bvt_kernel, dim3(NJ / 64), dim3(256), 0, stream,
                       feat, hid, Ww, bw, BvT);
    hipLaunchKernelGGL(score_ctx_kernel, dim3(NF / 2), dim3(256), 0, stream,
                       feat, hid, Ww, Wu, BvT, mask, ctx);
    hipLaunchKernelGGL(out_mm_kernel, dim3(BATCH / 32), dim3(256), 0, stream,
                       values, ctx, out);
}

// Round 2
// 191.027 us; speedup vs baseline: 1.4257x; 1.4257x over previous
//
#include <hip/hip_runtime.h>
#include <hip/hip_bf16.h>

#define NF   1024   // N features
#define NHID 256    // H hidden
#define NJ   1280   // N+H keys
#define ED   64     // E = HD = 64
#define BATCH 8192
#define SCB  320    // score block threads (5 waves); 4*320 = 1280 = NJ

__device__ __forceinline__ float fast_tanh(float x) {
    // tanh(x) = (e^{2x}-1)/(e^{2x}+1); exact identity, __expf ~2ulp, rcp ~1ulp
    float e = __expf(2.0f * x);
    float r = __builtin_amdgcn_rcpf(e + 1.0f);
    return (e - 1.0f) * r;
}

// ---- Kernel 1: AB[r][e]:  r<1024 -> A = feat@W1 ;  r>=1024 -> Bv = full@W2 + bw ----
// 72 blocks x 32 rows. Per-lane weight column in regs; input rows via wave-uniform float4.
__global__ __launch_bounds__(256) void prep_kernel(
    const float* __restrict__ feat, const float* __restrict__ hid,
    const float* __restrict__ Ww, const float* __restrict__ bw,
    float* __restrict__ AB)
{
    const int tid = threadIdx.x;
    const int e   = tid & 63;
    const int wv  = tid >> 6;            // wave 0..3, 8 rows each
    const int r0  = blockIdx.x * 32;
    const bool isA = (r0 < NF);
    const float* W = isA ? Ww : (Ww + 64 * 64);

    float wcol[64];
    #pragma unroll
    for (int k = 0; k < 64; k++) wcol[k] = W[k * 64 + e];   // coalesced column load
    const float bias = isA ? 0.f : bw[e];

    for (int rr = 0; rr < 8; rr++) {
        int r  = r0 + wv * 8 + rr;
        int jf = isA ? r : (r - NF);
        jf = __builtin_amdgcn_readfirstlane(jf);            // wave-uniform -> sgpr
        const float* in = (jf < NF) ? (feat + (size_t)jf * 64)
                                    : (hid  + (size_t)(jf - NF) * 64);
        float a0 = 0.f, a1 = 0.f, a2 = 0.f, a3 = 0.f;
        #pragma unroll
        for (int k4 = 0; k4 < 64; k4 += 16) {
            float4 q0 = *(const float4*)(in + k4);
            float4 q1 = *(const float4*)(in + k4 + 4);
            float4 q2 = *(const float4*)(in + k4 + 8);
            float4 q3 = *(const float4*)(in + k4 + 12);
            a0 += q0.x*wcol[k4+0] + q0.y*wcol[k4+1] + q0.z*wcol[k4+2] + q0.w*wcol[k4+3];
            a1 += q1.x*wcol[k4+4] + q1.y*wcol[k4+5] + q1.z*wcol[k4+6] + q1.w*wcol[k4+7];
            a2 += q2.x*wcol[k4+8] + q2.y*wcol[k4+9] + q2.z*wcol[k4+10]+ q2.w*wcol[k4+11];
            a3 += q3.x*wcol[k4+12]+ q3.y*wcol[k4+13]+ q3.z*wcol[k4+14]+ q3.w*wcol[k4+15];
        }
        AB[(size_t)r * 64 + e] = (a0 + a1) + (a2 + a3) + bias;
    }
}

// ---- Kernel 2: fused score / masked exp / rowsum / context.  2 rows per block. ----
// 512 blocks x 320 threads (5 waves) = 10 waves/CU. Per-lane row-major Bv float4 loads.
__global__ __launch_bounds__(SCB) void score_ctx_kernel(
    const float* __restrict__ feat, const float* __restrict__ hid,
    const float* __restrict__ Wu, const float* __restrict__ AB,
    const void* __restrict__ maskp, float* __restrict__ ctx)
{
    __shared__ __align__(16) float sA[2][64];
    __shared__ __align__(16) float sWu[64];
    __shared__ __align__(16) float sc[2][NJ];
    __shared__ __align__(16) float red[2][20][64];
    __shared__ float wpart[2][5];
    __shared__ float ssum[2];
    __shared__ int   mtype_s;

    const int tid = threadIdx.x;
    const int i0  = blockIdx.x * 2;

    if (tid < 64) {
        // detect mask encoding (uint8 / int32 / float32) from first 64 words
        const unsigned int* mw = (const unsigned int*)maskp;
        unsigned int w = mw[tid];
        unsigned long long notf = __ballot(w != 0u && w != 0x3F800000u);
        unsigned long long gt1  = __ballot(w > 1u);
        if (tid == 0) mtype_s = (notf == 0ull) ? 2 : ((gt1 == 0ull) ? 1 : 0);
        sWu[tid]   = Wu[tid];
        sA[0][tid] = AB[(size_t)i0 * 64 + tid];
        sA[1][tid] = AB[(size_t)(i0 + 1) * 64 + tid];
    }
    __syncthreads();

    const float* Bv = AB + (size_t)NF * 64;     // rows 1024.. of AB
    const int mtype = mtype_s;

    // ---- phase 1: scores.  Each thread: 4 j's x 2 rows, e-quad outer. ----
    float acc00 = 0.f, acc01 = 0.f, acc10 = 0.f, acc11 = 0.f;
    float acc20 = 0.f, acc21 = 0.f, acc30 = 0.f, acc31 = 0.f;
    for (int eq = 0; eq < 64; eq += 4) {
        float4 a0 = *(const float4*)&sA[0][eq];     // LDS broadcast
        float4 a1 = *(const float4*)&sA[1][eq];
        float4 wu = *(const float4*)&sWu[eq];
        float4 b0 = *(const float4*)(Bv + (size_t)(0 * SCB + tid) * 64 + eq);
        float4 b1 = *(const float4*)(Bv + (size_t)(1 * SCB + tid) * 64 + eq);
        float4 b2 = *(const float4*)(Bv + (size_t)(2 * SCB + tid) * 64 + eq);
        float4 b3 = *(const float4*)(Bv + (size_t)(3 * SCB + tid) * 64 + eq);
        acc00 += wu.x*fast_tanh(a0.x+b0.x) + wu.y*fast_tanh(a0.y+b0.y)
               + wu.z*fast_tanh(a0.z+b0.z) + wu.w*fast_tanh(a0.w+b0.w);
        acc01 += wu.x*fast_tanh(a1.x+b0.x) + wu.y*fast_tanh(a1.y+b0.y)
               + wu.z*fast_tanh(a1.z+b0.z) + wu.w*fast_tanh(a1.w+b0.w);
        acc10 += wu.x*fast_tanh(a0.x+b1.x) + wu.y*fast_tanh(a0.y+b1.y)
               + wu.z*fast_tanh(a0.z+b1.z) + wu.w*fast_tanh(a0.w+b1.w);
        acc11 += wu.x*fast_tanh(a1.x+b1.x) + wu.y*fast_tanh(a1.y+b1.y)
               + wu.z*fast_tanh(a1.z+b1.z) + wu.w*fast_tanh(a1.w+b1.w);
        acc20 += wu.x*fast_tanh(a0.x+b2.x) + wu.y*fast_tanh(a0.y+b2.y)
               + wu.z*fast_tanh(a0.z+b2.z) + wu.w*fast_tanh(a0.w+b2.w);
        acc21 += wu.x*fast_tanh(a1.x+b2.x) + wu.y*fast_tanh(a1.y+b2.y)
               + wu.z*fast_tanh(a1.z+b2.z) + wu.w*fast_tanh(a1.w+b2.w);
        acc30 += wu.x*fast_tanh(a0.x+b3.x) + wu.y*fast_tanh(a0.y+b3.y)
               + wu.z*fast_tanh(a0.z+b3.z) + wu.w*fast_tanh(a0.w+b3.w);
        acc31 += wu.x*fast_tanh(a1.x+b3.x) + wu.y*fast_tanh(a1.y+b3.y)
               + wu.z*fast_tanh(a1.z+b3.z) + wu.w*fast_tanh(a1.w+b3.w);
    }

    const unsigned char* m8  = (const unsigned char*)maskp;
    const unsigned int*  m32 = (const unsigned int*)maskp;
    const float*         mfl = (const float*)maskp;
    float lsum0 = 0.f, lsum1 = 0.f;
    float s0v[4] = {acc00, acc10, acc20, acc30};
    float s1v[4] = {acc01, acc11, acc21, acc31};
    #pragma unroll
    for (int jj = 0; jj < 4; jj++) {
        int j = jj * SCB + tid;
        size_t off0 = (size_t)i0 * NJ + j, off1 = off0 + NJ;
        bool b0, b1;
        if (mtype == 0)      { b0 = m8[off0]  != 0;   b1 = m8[off1]  != 0;   }
        else if (mtype == 1) { b0 = m32[off0] != 0u;  b1 = m32[off1] != 0u;  }
        else                 { b0 = mfl[off0] != 0.f; b1 = mfl[off1] != 0.f; }
        float e0 = b0 ? __expf(s0v[jj]) : 0.f;
        float e1 = b1 ? __expf(s1v[jj]) : 0.f;
        sc[0][j] = e0; sc[1][j] = e1;
        lsum0 += e0; lsum1 += e1;
    }
    #pragma unroll
    for (int off = 32; off > 0; off >>= 1) {
        lsum0 += __shfl_down(lsum0, off);
        lsum1 += __shfl_down(lsum1, off);
    }
    if ((tid & 63) == 0) { wpart[0][tid >> 6] = lsum0; wpart[1][tid >> 6] = lsum1; }
    __syncthreads();
    if (tid < 2) {
        float s = wpart[tid][0] + wpart[tid][1] + wpart[tid][2] + wpart[tid][3] + wpart[tid][4];
        ssum[tid] = (s == 0.f) ? 1.f : s;
    }
    __syncthreads();

    // ---- phase 2: ctx[i][e] = sum_j sc[i][j] * full[j][e] / ssum ----
    const int e4 = (tid & 15) * 4;
    const int jg = tid >> 4;                    // 0..19
    float4 c0 = {0.f,0.f,0.f,0.f}, c1 = {0.f,0.f,0.f,0.f};
    for (int it = 0; it < 64; it++) {
        int j = it * 20 + jg;
        const float* fr = (j < NF) ? (feat + (size_t)j * 64)
                                   : (hid  + (size_t)(j - NF) * 64);
        float4 f = *(const float4*)(fr + e4);
        float w0 = sc[0][j], w1 = sc[1][j];
        c0.x += w0*f.x; c0.y += w0*f.y; c0.z += w0*f.z; c0.w += w0*f.w;
        c1.x += w1*f.x; c1.y += w1*f.y; c1.z += w1*f.z; c1.w += w1*f.w;
    }
    *(float4*)&red[0][jg][e4] = c0;
    *(float4*)&red[1][jg][e4] = c1;
    __syncthreads();
    if (tid < 128) {
        int half = tid >> 6, e = tid & 63;
        float v = 0.f;
        #pragma unroll
        for (int g = 0; g < 20; g++) v += red[half][g][e];
        ctx[(size_t)(i0 + half) * 64 + e] = v / ssum[half];
    }
}

// ---- Kernel 3: out = values(8192x1024) @ ctx(1024x64) ----
// 512 blocks x 16 rows. lane = output column; wave = K-quarter; ctx chunk in 64 regs;
// values rows read as wave-uniform float4 (scalarizable). LDS only for final reduce.
__global__ __launch_bounds__(256) void out_mm_kernel(
    const float* __restrict__ values, const float* __restrict__ ctxp,
    float* __restrict__ out)
{
    __shared__ __align__(16) float red[4][16][64];   // 16 KB
    const int tid  = threadIdx.x;
    const int lane = tid & 63;
    const int wv   = tid >> 6;                       // K-quarter owner
    const int r0   = blockIdx.x * 16;
    const int kbase = __builtin_amdgcn_readfirstlane(wv * 256);

    float acc[16];
    #pragma unroll
    for (int r = 0; r < 16; r++) acc[r] = 0.f;
    float creg[64];

    for (int c = 0; c < 4; c++) {                    // 4 chunks of K=64
        const int k0 = kbase + c * 64;
        #pragma unroll
        for (int kk = 0; kk < 64; kk++)              // coalesced ctx column load
            creg[kk] = ctxp[(size_t)(k0 + kk) * 64 + lane];
        #pragma unroll
        for (int r = 0; r < 16; r++) {
            const float* vrow = values + (size_t)(r0 + r) * NF + k0;
            float p0 = 0.f, p1 = 0.f, p2 = 0.f, p3 = 0.f;
            #pragma unroll
            for (int k4 = 0; k4 < 64; k4 += 16) {
                float4 q0 = *(const float4*)(vrow + k4);       // wave-uniform addr
                float4 q1 = *(const float4*)(vrow + k4 + 4);
                float4 q2 = *(const float4*)(vrow + k4 + 8);
                float4 q3 = *(const float4*)(vrow + k4 + 12);
                p0 += q0.x*creg[k4+0] + q0.y*creg[k4+1] + q0.z*creg[k4+2] + q0.w*creg[k4+3];
                p1 += q1.x*creg[k4+4] + q1.y*creg[k4+5] + q1.z*creg[k4+6] + q1.w*creg[k4+7];
                p2 += q2.x*creg[k4+8] + q2.y*creg[k4+9] + q2.z*creg[k4+10]+ q2.w*creg[k4+11];
                p3 += q3.x*creg[k4+12]+ q3.y*creg[k4+13]+ q3.z*creg[k4+14]+ q3.w*creg[k4+15];
            }
            acc[r] += (p0 + p1) + (p2 + p3);
        }
    }
    #pragma unroll
    for (int r = 0; r < 16; r++) red[wv][r][lane] = acc[r];
    __syncthreads();
    #pragma unroll
    for (int rr = 0; rr < 4; rr++) {
        int r = wv + rr * 4;
        float v = red[0][r][lane] + red[1][r][lane] + red[2][r][lane] + red[3][r][lane];
        out[(size_t)(r0 + r) * 64 + lane] = v;
    }
}

extern "C" void kernel_launch(void* const* d_in, const int* in_sizes, int n_in,
                              void* d_out, int out_size, void* d_ws, size_t ws_size,
                              hipStream_t stream) {
    const float* values = (const float*)d_in[0];
    const float* feat   = (const float*)d_in[1];
    const float* hid    = (const float*)d_in[2];
    const float* Ww     = (const float*)d_in[3];
    const float* bw     = (const float*)d_in[4];
    const float* Wu     = (const float*)d_in[5];
    const void*  mask   = d_in[6];
    float* out = (float*)d_out;

    float* AB  = (float*)d_ws;                                    // 2304*64*4 = 576 KiB
    float* ctx = (float*)((char*)d_ws + (size_t)(NF + NJ) * 64 * 4);  // 1024*64*4 = 256 KiB

    hipLaunchKernelGGL(prep_kernel, dim3((NF + NJ) / 32), dim3(256), 0, stream,
                       feat, hid, Ww, bw, AB);
    hipLaunchKernelGGL(score_ctx_kernel, dim3(NF / 2), dim3(SCB), 0, stream,
                       feat, hid, Wu, AB, mask, ctx);
    hipLaunchKernelGGL(out_mm_kernel, dim3(BATCH / 16), dim3(256), 0, stream,
                       values, ctx, out);
}

// Round 3
// 185.502 us; speedup vs baseline: 1.4681x; 1.0298x over previous
//
#include <hip/hip_runtime.h>
#include <hip/hip_bf16.h>

#define NF   1024   // N features
#define NHID 256    // H hidden
#define NJ   1280   // N+H keys
#define ED   64     // E = HD = 64
#define BATCH 8192

__device__ __forceinline__ float fast_tanh(float x) {
    // tanh(x) = (e^{2x}-1)/(e^{2x}+1); __expf ~2ulp, rcp ~1ulp
    float e = __expf(2.0f * x);
    float r = __builtin_amdgcn_rcpf(e + 1.0f);
    return (e - 1.0f) * r;
}

// ---- Kernel 1: AB[r][e]:  r<1024 -> A = feat@W1 ;  r>=1024 -> Bv = full@W2 + bw ----
__global__ __launch_bounds__(256) void prep_kernel(
    const float* __restrict__ feat, const float* __restrict__ hid,
    const float* __restrict__ Ww, const float* __restrict__ bw,
    float* __restrict__ AB)
{
    const int tid = threadIdx.x;
    const int e   = tid & 63;
    const int wv  = tid >> 6;
    const int r0  = blockIdx.x * 32;
    const bool isA = (r0 < NF);
    const float* W = isA ? Ww : (Ww + 64 * 64);

    float wcol[64];
    #pragma unroll
    for (int k = 0; k < 64; k++) wcol[k] = W[k * 64 + e];
    const float bias = isA ? 0.f : bw[e];

    for (int rr = 0; rr < 8; rr++) {
        int r  = r0 + wv * 8 + rr;
        int jf = isA ? r : (r - NF);
        jf = __builtin_amdgcn_readfirstlane(jf);
        const float* in = (jf < NF) ? (feat + (size_t)jf * 64)
                                    : (hid  + (size_t)(jf - NF) * 64);
        float a0 = 0.f, a1 = 0.f, a2 = 0.f, a3 = 0.f;
        #pragma unroll
        for (int k4 = 0; k4 < 64; k4 += 16) {
            float4 q0 = *(const float4*)(in + k4);
            float4 q1 = *(const float4*)(in + k4 + 4);
            float4 q2 = *(const float4*)(in + k4 + 8);
            float4 q3 = *(const float4*)(in + k4 + 12);
            a0 += q0.x*wcol[k4+0] + q0.y*wcol[k4+1] + q0.z*wcol[k4+2] + q0.w*wcol[k4+3];
            a1 += q1.x*wcol[k4+4] + q1.y*wcol[k4+5] + q1.z*wcol[k4+6] + q1.w*wcol[k4+7];
            a2 += q2.x*wcol[k4+8] + q2.y*wcol[k4+9] + q2.z*wcol[k4+10]+ q2.w*wcol[k4+11];
            a3 += q3.x*wcol[k4+12]+ q3.y*wcol[k4+13]+ q3.z*wcol[k4+14]+ q3.w*wcol[k4+15];
        }
        AB[(size_t)r * 64 + e] = (a0 + a1) + (a2 + a3) + bias;
    }
}

// ---- Kernel 2: per-row mask compaction (order within a row is irrelevant) ----
__global__ __launch_bounds__(256) void compact_kernel(
    const void* __restrict__ maskp, unsigned short* __restrict__ idx,
    int* __restrict__ cnt)
{
    __shared__ int cnt_s;
    __shared__ int mtype_s;
    const int tid = threadIdx.x;
    const int i   = blockIdx.x;
    if (tid == 0) cnt_s = 0;
    if (tid < 64) {
        const unsigned int* mw = (const unsigned int*)maskp;
        unsigned int w = mw[tid];
        unsigned long long notf = __ballot(w != 0u && w != 0x3F800000u);
        unsigned long long gt1  = __ballot(w > 1u);
        if (tid == 0) mtype_s = (notf == 0ull) ? 2 : ((gt1 == 0ull) ? 1 : 0);
    }
    __syncthreads();
    const int mtype = mtype_s;
    const unsigned char* m8  = (const unsigned char*)maskp;
    const unsigned int*  m32 = (const unsigned int*)maskp;
    const float*         mfl = (const float*)maskp;
    const int lane = tid & 63;

    #pragma unroll
    for (int chunk = 0; chunk < 5; chunk++) {
        int j = chunk * 256 + tid;
        size_t off = (size_t)i * NJ + j;
        bool a;
        if (mtype == 0)      a = m8[off]  != 0;
        else if (mtype == 1) a = m32[off] != 0u;
        else                 a = mfl[off] != 0.f;
        unsigned long long bal = __ballot(a);
        int pos = __popcll(bal & ((1ull << lane) - 1ull));
        int tot = __popcll(bal);
        int base = 0;
        if (lane == 0) base = atomicAdd(&cnt_s, tot);
        base = __shfl(base, 0);
        if (a) idx[(size_t)i * NJ + base + pos] = (unsigned short)j;
    }
    __syncthreads();
    if (tid == 0) cnt[i] = cnt_s;
}

// ---- Kernel 3: fused score/exp/rowsum/context, one row per block, compacted j ----
__global__ __launch_bounds__(256) void score_ctx_kernel(
    const float* __restrict__ feat, const float* __restrict__ hid,
    const float* __restrict__ Wu, const float* __restrict__ AB,
    const unsigned short* __restrict__ idx, const int* __restrict__ cntp,
    float* __restrict__ ctx)
{
    __shared__ __align__(16) float sA[64];
    __shared__ __align__(16) float sWu[64];
    __shared__ __align__(16) float sc_s[NJ];
    __shared__ __align__(16) float red[16][68];
    __shared__ float wpart[4];
    __shared__ float ssum_s;

    const int tid = threadIdx.x;
    const int i   = blockIdx.x;
    const int cnt = cntp[i];

    if (tid < 64) { sA[tid] = AB[(size_t)i * 64 + tid]; sWu[tid] = Wu[tid]; }
    __syncthreads();

    const float* Bv = AB + (size_t)NF * 64;
    float lsum = 0.f;
    for (int c = tid; c < cnt; c += 256) {
        int j = idx[(size_t)i * NJ + c];
        const float* bp = Bv + (size_t)j * 64;
        float a0 = 0.f, a1 = 0.f, a2 = 0.f, a3 = 0.f;
        #pragma unroll
        for (int eq = 0; eq < 64; eq += 4) {
            float4 b = *(const float4*)(bp + eq);
            float4 a = *(const float4*)&sA[eq];
            float4 w = *(const float4*)&sWu[eq];
            a0 += w.x * fast_tanh(a.x + b.x);
            a1 += w.y * fast_tanh(a.y + b.y);
            a2 += w.z * fast_tanh(a.z + b.z);
            a3 += w.w * fast_tanh(a.w + b.w);
        }
        float val = __expf((a0 + a1) + (a2 + a3));
        sc_s[c] = val;
        lsum += val;
    }
    #pragma unroll
    for (int off = 32; off > 0; off >>= 1) lsum += __shfl_down(lsum, off);
    if ((tid & 63) == 0) wpart[tid >> 6] = lsum;
    __syncthreads();
    if (tid == 0) {
        float s = wpart[0] + wpart[1] + wpart[2] + wpart[3];
        ssum_s = (cnt == 0) ? 1.f : s;
    }
    __syncthreads();

    // phase 2: ctx[i][e] = (1/ssum) * sum_c sc[c] * full[idx[c]][e]
    const int cg = tid >> 4;            // 0..15
    const int e4 = (tid & 15) * 4;
    float4 acc = {0.f, 0.f, 0.f, 0.f};
    for (int c = cg; c < cnt; c += 16) {
        int j = idx[(size_t)i * NJ + c];
        const float* fr = (j < NF) ? (feat + (size_t)j * 64)
                                   : (hid  + (size_t)(j - NF) * 64);
        float4 f = *(const float4*)(fr + e4);
        float wv = sc_s[c];
        acc.x += wv * f.x; acc.y += wv * f.y; acc.z += wv * f.z; acc.w += wv * f.w;
    }
    *(float4*)&red[cg][e4] = acc;
    __syncthreads();
    if (tid < 64) {
        float v = 0.f;
        #pragma unroll
        for (int g = 0; g < 16; g++) v += red[g][tid];
        ctx[(size_t)i * 64 + tid] = v / ssum_s;
    }
}

// ---- Kernel 4: out = values(8192x1024) @ ctx(1024x64), LDS-tiled fp32 GEMM ----
// 512 blocks = 128 row-tiles x 4 K-quarters. 64x64 tile, 4x4 per thread.
// V tile stored transposed [k][r] with float4-chunk XOR-ish swizzle p=(rchunk+k/4)&15:
// staging scalar writes 2-way free; compute reads broadcast conflict-free b128.
__global__ __launch_bounds__(256) void out_mm_kernel(
    const float* __restrict__ values, const float* __restrict__ ctxp,
    float* __restrict__ out)
{
    __shared__ __align__(16) float vsT[64 * 64];   // 16 KB
    __shared__ __align__(16) float cs[64][64];     // 16 KB
    const int tid = threadIdx.x;
    const int rt  = blockIdx.x >> 2;
    const int kq  = blockIdx.x & 3;
    const int r0  = rt * 64;
    const int tr  = tid >> 4;            // row chunk 0..15 (4 rows)
    const int tc4 = (tid & 15) * 4;      // col base

    float acc[4][4];
    #pragma unroll
    for (int a = 0; a < 4; a++)
        #pragma unroll
        for (int b = 0; b < 4; b++) acc[a][b] = 0.f;

    for (int ch = 0; ch < 4; ch++) {
        const int k0 = kq * 256 + ch * 64;
        __syncthreads();
        #pragma unroll
        for (int s = 0; s < 4; s++) {           // stage V transposed+swizzled
            int t   = tid + s * 256;
            int r   = t >> 4;                   // 0..63
            int kk4 = (t & 15) * 4;
            float4 g = *(const float4*)&values[(size_t)(r0 + r) * NF + k0 + kk4];
            int p  = (((r >> 2) + (t & 15)) & 15) * 4 + (r & 3);
            vsT[(kk4 + 0) * 64 + p] = g.x;
            vsT[(kk4 + 1) * 64 + p] = g.y;
            vsT[(kk4 + 2) * 64 + p] = g.z;
            vsT[(kk4 + 3) * 64 + p] = g.w;
        }
        #pragma unroll
        for (int s = 0; s < 4; s++) {           // stage ctx tile
            int t  = tid + s * 256;
            int kk = t >> 4;
            int c4 = (t & 15) * 4;
            *(float4*)&cs[kk][c4] = *(const float4*)&ctxp[(size_t)(k0 + kk) * ED + c4];
        }
        __syncthreads();
        #pragma unroll 8
        for (int k = 0; k < 64; k++) {
            float4 av = *(const float4*)&vsT[k * 64 + (((tr + (k >> 2)) & 15) << 2)];
            float4 bv = *(const float4*)&cs[k][tc4];
            acc[0][0] += av.x*bv.x; acc[0][1] += av.x*bv.y; acc[0][2] += av.x*bv.z; acc[0][3] += av.x*bv.w;
            acc[1][0] += av.y*bv.x; acc[1][1] += av.y*bv.y; acc[1][2] += av.y*bv.z; acc[1][3] += av.y*bv.w;
            acc[2][0] += av.z*bv.x; acc[2][1] += av.z*bv.y; acc[2][2] += av.z*bv.z; acc[2][3] += av.z*bv.w;
            acc[3][0] += av.w*bv.x; acc[3][1] += av.w*bv.y; acc[3][2] += av.w*bv.z; acc[3][3] += av.w*bv.w;
        }
    }
    #pragma unroll
    for (int i2 = 0; i2 < 4; i2++) {
        int r = r0 + tr * 4 + i2;
        float* op = out + (size_t)r * ED + tc4;
        unsafeAtomicAdd(op + 0, acc[i2][0]);
        unsafeAtomicAdd(op + 1, acc[i2][1]);
        unsafeAtomicAdd(op + 2, acc[i2][2]);
        unsafeAtomicAdd(op + 3, acc[i2][3]);
    }
}

extern "C" void kernel_launch(void* const* d_in, const int* in_sizes, int n_in,
                              void* d_out, int out_size, void* d_ws, size_t ws_size,
                              hipStream_t stream) {
    const float* values = (const float*)d_in[0];
    const float* feat   = (const float*)d_in[1];
    const float* hid    = (const float*)d_in[2];
    const float* Ww     = (const float*)d_in[3];
    const float* bw     = (const float*)d_in[4];
    const float* Wu     = (const float*)d_in[5];
    const void*  mask   = d_in[6];
    float* out = (float*)d_out;

    float* AB  = (float*)d_ws;                               // 2304*64*4 = 576 KiB
    float* ctx = AB + (size_t)(NF + NJ) * 64;                // 256 KiB
    unsigned short* idx = (unsigned short*)(ctx + (size_t)NF * 64);  // 1024*1280*2 = 2.5 MiB
    int* cnt = (int*)(idx + (size_t)NF * NJ);                // 4 KiB

    hipMemsetAsync(d_out, 0, (size_t)BATCH * ED * sizeof(float), stream);
    hipLaunchKernelGGL(prep_kernel, dim3((NF + NJ) / 32), dim3(256), 0, stream,
                       feat, hid, Ww, bw, AB);
    hipLaunchKernelGGL(compact_kernel, dim3(NF), dim3(256), 0, stream,
                       mask, idx, cnt);
    hipLaunchKernelGGL(score_ctx_kernel, dim3(NF), dim3(256), 0, stream,
                       feat, hid, Wu, AB, idx, cnt, ctx);
    hipLaunchKernelGGL(out_mm_kernel, dim3(512), dim3(256), 0, stream,
                       values, ctx, out);
}

// Round 4
// 148.230 us; speedup vs baseline: 1.8373x; 1.2514x over previous
//
#include <hip/hip_runtime.h>
#include <hip/hip_bf16.h>

#define NF   1024   // N features
#define NHID 256    // H hidden
#define NJ   1280   // N+H keys
#define ED   64     // E = HD = 64
#define BATCH 8192
#define SCB  320    // score block threads (5 waves); 320*4 = 1280 = NJ

#if defined(__has_builtin) && __has_builtin(__builtin_amdgcn_exp2f)
#define EXP2(x) __builtin_amdgcn_exp2f(x)
#else
#define EXP2(x) exp2f(x)
#endif
#define K2E 2.8853900817779268f   // 2*log2(e):  exp(2x) = exp2(K2E*x)

// ---- Kernel 1: A[i][e] = feat@W1 ; BvT[e][j] = (full@W2 + bw) transposed ----
__global__ __launch_bounds__(256) void prep_kernel(
    const float* __restrict__ feat, const float* __restrict__ hid,
    const float* __restrict__ Ww, const float* __restrict__ bw,
    float* __restrict__ A, float* __restrict__ BvT)
{
    __shared__ float tile[32][65];
    const int tid = threadIdx.x;
    const int e   = tid & 63;
    const int wv  = tid >> 6;
    const int r0  = blockIdx.x * 32;
    const bool isA = (r0 < NF);
    const float* W = isA ? Ww : (Ww + 64 * 64);

    float wcol[64];
    #pragma unroll
    for (int k = 0; k < 64; k++) wcol[k] = W[k * 64 + e];
    const float bias = isA ? 0.f : bw[e];

    #pragma unroll
    for (int rr = 0; rr < 8; rr++) {
        int r  = r0 + wv * 8 + rr;
        int jf = isA ? r : (r - NF);
        jf = __builtin_amdgcn_readfirstlane(jf);
        const float* in = (jf < NF) ? (feat + (size_t)jf * 64)
                                    : (hid  + (size_t)(jf - NF) * 64);
        float a0 = 0.f, a1 = 0.f, a2 = 0.f, a3 = 0.f;
        #pragma unroll
        for (int k4 = 0; k4 < 64; k4 += 16) {
            float4 q0 = *(const float4*)(in + k4);
            float4 q1 = *(const float4*)(in + k4 + 4);
            float4 q2 = *(const float4*)(in + k4 + 8);
            float4 q3 = *(const float4*)(in + k4 + 12);
            a0 += q0.x*wcol[k4+0] + q0.y*wcol[k4+1] + q0.z*wcol[k4+2] + q0.w*wcol[k4+3];
            a1 += q1.x*wcol[k4+4] + q1.y*wcol[k4+5] + q1.z*wcol[k4+6] + q1.w*wcol[k4+7];
            a2 += q2.x*wcol[k4+8] + q2.y*wcol[k4+9] + q2.z*wcol[k4+10]+ q2.w*wcol[k4+11];
            a3 += q3.x*wcol[k4+12]+ q3.y*wcol[k4+13]+ q3.z*wcol[k4+14]+ q3.w*wcol[k4+15];
        }
        float res = (a0 + a1) + (a2 + a3) + bias;
        if (isA) A[(size_t)r * 64 + e] = res;
        else     tile[wv * 8 + rr][e] = res;
    }
    if (!isA) {
        __syncthreads();
        const int j0 = r0 - NF;
        const int ee = tid >> 2;
        #pragma unroll
        for (int h = 0; h < 2; h++) {
            int c = (tid & 3) + h * 4;          // 8 chunks of 4 rows
            float4 v;
            v.x = tile[c * 4 + 0][ee];
            v.y = tile[c * 4 + 1][ee];
            v.z = tile[c * 4 + 2][ee];
            v.w = tile[c * 4 + 3][ee];
            *(float4*)&BvT[(size_t)ee * NJ + j0 + c * 4] = v;
        }
    }
}

// ---- Kernel 2: fused score / masked exp / rowsum / context.  I=2 rows/block ----
// 512 blocks x 320 threads. Lane owns 4 consecutive j: BvT loads coalesced float4.
__global__ __launch_bounds__(SCB) void score_ctx_kernel(
    const float* __restrict__ feat, const float* __restrict__ hid,
    const float* __restrict__ Wu, const float* __restrict__ A,
    const float* __restrict__ BvT, const void* __restrict__ maskp,
    float* __restrict__ ctx)
{
    __shared__ __align__(16) float4 sPack[64];       // {a0,a1,wu,0}
    __shared__ __align__(16) float sc0[NJ], sc1[NJ];
    __shared__ __align__(16) float red[2][20][64];
    __shared__ float wpart[2][5];
    __shared__ float ssum[2];
    __shared__ float sSwu;
    __shared__ int   mtype_s;

    const int tid = threadIdx.x;
    const int i0  = blockIdx.x * 2;

    if (tid < 64) {
        const unsigned int* mw = (const unsigned int*)maskp;
        unsigned int w = mw[tid];
        unsigned long long notf = __ballot(w != 0u && w != 0x3F800000u);
        unsigned long long gt1  = __ballot(w > 1u);
        if (tid == 0) mtype_s = (notf == 0ull) ? 2 : ((gt1 == 0ull) ? 1 : 0);
        float wu = Wu[tid];
        float4 p;
        p.x = A[(size_t)i0 * 64 + tid];
        p.y = A[(size_t)(i0 + 1) * 64 + tid];
        p.z = wu; p.w = 0.f;
        sPack[tid] = p;
        float s = wu;
        #pragma unroll
        for (int off = 32; off > 0; off >>= 1) s += __shfl_down(s, off);
        if (tid == 0) sSwu = s;
    }
    __syncthreads();

    const int j4 = tid * 4;
    float4 acc0 = {0.f,0.f,0.f,0.f};   // row i0,   4 j's:  sum wu*rcp(exp(2x)+1)
    float4 acc1 = {0.f,0.f,0.f,0.f};   // row i0+1
    #pragma unroll 4
    for (int e = 0; e < 64; e++) {
        float4 b = *(const float4*)(BvT + (size_t)e * NJ + j4);
        float4 p = sPack[e];
        float x, r;
        x = p.x + b.x; r = __builtin_amdgcn_rcpf(EXP2(x * K2E) + 1.f); acc0.x = fmaf(p.z, r, acc0.x);
        x = p.x + b.y; r = __builtin_amdgcn_rcpf(EXP2(x * K2E) + 1.f); acc0.y = fmaf(p.z, r, acc0.y);
        x = p.x + b.z; r = __builtin_amdgcn_rcpf(EXP2(x * K2E) + 1.f); acc0.z = fmaf(p.z, r, acc0.z);
        x = p.x + b.w; r = __builtin_amdgcn_rcpf(EXP2(x * K2E) + 1.f); acc0.w = fmaf(p.z, r, acc0.w);
        x = p.y + b.x; r = __builtin_amdgcn_rcpf(EXP2(x * K2E) + 1.f); acc1.x = fmaf(p.z, r, acc1.x);
        x = p.y + b.y; r = __builtin_amdgcn_rcpf(EXP2(x * K2E) + 1.f); acc1.y = fmaf(p.z, r, acc1.y);
        x = p.y + b.z; r = __builtin_amdgcn_rcpf(EXP2(x * K2E) + 1.f); acc1.z = fmaf(p.z, r, acc1.z);
        x = p.y + b.w; r = __builtin_amdgcn_rcpf(EXP2(x * K2E) + 1.f); acc1.w = fmaf(p.z, r, acc1.w);
    }
    const float Swu = sSwu;
    // score = Swu - 2*acc ; then mask & exp
    const int mtype = mtype_s;
    const unsigned char* m8  = (const unsigned char*)maskp;
    const unsigned int*  m32 = (const unsigned int*)maskp;
    const float*         mfl = (const float*)maskp;
    bool b00,b01,b02,b03, b10,b11,b12,b13;
    if (mtype == 0) {
        unsigned m0 = *(const unsigned*)(m8 + (size_t)i0 * NJ + j4);
        unsigned m1 = *(const unsigned*)(m8 + (size_t)(i0+1) * NJ + j4);
        b00 = m0 & 0xffu; b01 = m0 & 0xff00u; b02 = m0 & 0xff0000u; b03 = m0 & 0xff000000u;
        b10 = m1 & 0xffu; b11 = m1 & 0xff00u; b12 = m1 & 0xff0000u; b13 = m1 & 0xff000000u;
    } else if (mtype == 1) {
        uint4 m0 = *(const uint4*)(m32 + (size_t)i0 * NJ + j4);
        uint4 m1 = *(const uint4*)(m32 + (size_t)(i0+1) * NJ + j4);
        b00 = m0.x; b01 = m0.y; b02 = m0.z; b03 = m0.w;
        b10 = m1.x; b11 = m1.y; b12 = m1.z; b13 = m1.w;
    } else {
        float4 m0 = *(const float4*)(mfl + (size_t)i0 * NJ + j4);
        float4 m1 = *(const float4*)(mfl + (size_t)(i0+1) * NJ + j4);
        b00 = m0.x != 0.f; b01 = m0.y != 0.f; b02 = m0.z != 0.f; b03 = m0.w != 0.f;
        b10 = m1.x != 0.f; b11 = m1.y != 0.f; b12 = m1.z != 0.f; b13 = m1.w != 0.f;
    }
    float4 e0, e1;
    e0.x = b00 ? __expf(Swu - 2.f*acc0.x) : 0.f;
    e0.y = b01 ? __expf(Swu - 2.f*acc0.y) : 0.f;
    e0.z = b02 ? __expf(Swu - 2.f*acc0.z) : 0.f;
    e0.w = b03 ? __expf(Swu - 2.f*acc0.w) : 0.f;
    e1.x = b10 ? __expf(Swu - 2.f*acc1.x) : 0.f;
    e1.y = b11 ? __expf(Swu - 2.f*acc1.y) : 0.f;
    e1.z = b12 ? __expf(Swu - 2.f*acc1.z) : 0.f;
    e1.w = b13 ? __expf(Swu - 2.f*acc1.w) : 0.f;
    *(float4*)&sc0[j4] = e0;
    *(float4*)&sc1[j4] = e1;
    float lsum0 = (e0.x + e0.y) + (e0.z + e0.w);
    float lsum1 = (e1.x + e1.y) + (e1.z + e1.w);
    #pragma unroll
    for (int off = 32; off > 0; off >>= 1) {
        lsum0 += __shfl_down(lsum0, off);
        lsum1 += __shfl_down(lsum1, off);
    }
    if ((tid & 63) == 0) { wpart[0][tid >> 6] = lsum0; wpart[1][tid >> 6] = lsum1; }
    __syncthreads();
    if (tid < 2) {
        float s = wpart[tid][0] + wpart[tid][1] + wpart[tid][2] + wpart[tid][3] + wpart[tid][4];
        ssum[tid] = (s == 0.f) ? 1.f : s;
    }
    __syncthreads();

    // ---- phase 2: ctx[i][e] = (1/ssum) * sum_j sc[i][j] * full[j][e] ----
    const int jg = tid >> 4;             // 0..19
    const int e4 = (tid & 15) * 4;
    float4 c0 = {0.f,0.f,0.f,0.f}, c1 = {0.f,0.f,0.f,0.f};
    for (int it = 0; it < 64; it++) {
        int j = it * 20 + jg;
        const float* fr = (j < NF) ? (feat + (size_t)j * 64)
                                   : (hid  + (size_t)(j - NF) * 64);
        float4 f = *(const float4*)(fr + e4);
        float w0 = sc0[j], w1 = sc1[j];
        c0.x += w0*f.x; c0.y += w0*f.y; c0.z += w0*f.z; c0.w += w0*f.w;
        c1.x += w1*f.x; c1.y += w1*f.y; c1.z += w1*f.z; c1.w += w1*f.w;
    }
    *(float4*)&red[0][jg][e4] = c0;
    *(float4*)&red[1][jg][e4] = c1;
    __syncthreads();
    if (tid < 128) {
        int half = tid >> 6, e = tid & 63;
        float v = 0.f;
        #pragma unroll
        for (int g = 0; g < 20; g++) v += red[half][g][e];
        ctx[(size_t)(i0 + half) * 64 + e] = v / ssum[half];
    }
}

// ---- Kernel 3: out = values(8192x1024) @ ctx(1024x64), 64x64 tile, 4-way k-split ----
// mode 0: write partials to part[kq];  mode 1: unsafeAtomicAdd into out (needs memset).
__global__ __launch_bounds__(256) void out_mm_kernel(
    const float* __restrict__ values, const float* __restrict__ ctxp,
    float* __restrict__ dst, int atomic_mode)
{
    __shared__ __align__(16) float vsT[64 * 64];
    __shared__ __align__(16) float cs[64][64];
    const int tid = threadIdx.x;
    const int rt  = blockIdx.x >> 2;
    const int kq  = blockIdx.x & 3;
    const int r0  = rt * 64;
    const int tr  = tid >> 4;
    const int tc4 = (tid & 15) * 4;

    float acc[4][4];
    #pragma unroll
    for (int a = 0; a < 4; a++)
        #pragma unroll
        for (int b = 0; b < 4; b++) acc[a][b] = 0.f;

    for (int ch = 0; ch < 4; ch++) {
        const int k0 = kq * 256 + ch * 64;
        __syncthreads();
        #pragma unroll
        for (int s = 0; s < 4; s++) {
            int t   = tid + s * 256;
            int r   = t >> 4;
            int kk4 = (t & 15) * 4;
            float4 g = *(const float4*)&values[(size_t)(r0 + r) * NF + k0 + kk4];
            int p  = (((r >> 2) + (t & 15)) & 15) * 4 + (r & 3);
            vsT[(kk4 + 0) * 64 + p] = g.x;
            vsT[(kk4 + 1) * 64 + p] = g.y;
            vsT[(kk4 + 2) * 64 + p] = g.z;
            vsT[(kk4 + 3) * 64 + p] = g.w;
        }
        #pragma unroll
        for (int s = 0; s < 4; s++) {
            int t  = tid + s * 256;
            int kk = t >> 4;
            int c4 = (t & 15) * 4;
            *(float4*)&cs[kk][c4] = *(const float4*)&ctxp[(size_t)(k0 + kk) * ED + c4];
        }
        __syncthreads();
        #pragma unroll 8
        for (int k = 0; k < 64; k++) {
            float4 av = *(const float4*)&vsT[k * 64 + (((tr + (k >> 2)) & 15) << 2)];
            float4 bv = *(const float4*)&cs[k][tc4];
            acc[0][0] += av.x*bv.x; acc[0][1] += av.x*bv.y; acc[0][2] += av.x*bv.z; acc[0][3] += av.x*bv.w;
            acc[1][0] += av.y*bv.x; acc[1][1] += av.y*bv.y; acc[1][2] += av.y*bv.z; acc[1][3] += av.y*bv.w;
            acc[2][0] += av.z*bv.x; acc[2][1] += av.z*bv.y; acc[2][2] += av.z*bv.z; acc[2][3] += av.z*bv.w;
            acc[3][0] += av.w*bv.x; acc[3][1] += av.w*bv.y; acc[3][2] += av.w*bv.z; acc[3][3] += av.w*bv.w;
        }
    }
    if (atomic_mode) {
        #pragma unroll
        for (int i2 = 0; i2 < 4; i2++) {
            int r = r0 + tr * 4 + i2;
            float* op = dst + (size_t)r * ED + tc4;
            unsafeAtomicAdd(op + 0, acc[i2][0]);
            unsafeAtomicAdd(op + 1, acc[i2][1]);
            unsafeAtomicAdd(op + 2, acc[i2][2]);
            unsafeAtomicAdd(op + 3, acc[i2][3]);
        }
    } else {
        #pragma unroll
        for (int i2 = 0; i2 < 4; i2++) {
            int r = r0 + tr * 4 + i2;
            float* op = dst + ((size_t)kq * BATCH + r) * ED + tc4;
            *(float4*)op = make_float4(acc[i2][0], acc[i2][1], acc[i2][2], acc[i2][3]);
        }
    }
}

// ---- Kernel 4: out = part0+part1+part2+part3 (float4) ----
__global__ __launch_bounds__(256) void reduce4_kernel(
    const float* __restrict__ part, float* __restrict__ out)
{
    const size_t S = (size_t)BATCH * ED / 4;      // float4 count per partial
    size_t idx = (size_t)blockIdx.x * 256 + threadIdx.x;
    const float4* p = (const float4*)part;
    float4 a = p[idx], b = p[idx + S], c = p[idx + 2*S], d = p[idx + 3*S];
    float4 r;
    r.x = (a.x + b.x) + (c.x + d.x);
    r.y = (a.y + b.y) + (c.y + d.y);
    r.z = (a.z + b.z) + (c.z + d.z);
    r.w = (a.w + b.w) + (c.w + d.w);
    ((float4*)out)[idx] = r;
}

extern "C" void kernel_launch(void* const* d_in, const int* in_sizes, int n_in,
                              void* d_out, int out_size, void* d_ws, size_t ws_size,
                              hipStream_t stream) {
    const float* values = (const float*)d_in[0];
    const float* feat   = (const float*)d_in[1];
    const float* hid    = (const float*)d_in[2];
    const float* Ww     = (const float*)d_in[3];
    const float* bw     = (const float*)d_in[4];
    const float* Wu     = (const float*)d_in[5];
    const void*  mask   = d_in[6];
    float* out = (float*)d_out;

    float* A    = (float*)d_ws;                        // 1024*64      = 256 KiB
    float* BvT  = A + (size_t)NF * 64;                 // 64*1280      = 320 KiB
    float* ctx  = BvT + (size_t)ED * NJ;               // 1024*64      = 256 KiB
    float* part = ctx + (size_t)NF * 64;               // 4*8192*64    = 8   MiB
    const size_t need = ((size_t)NF*64 + (size_t)ED*NJ + (size_t)NF*64
                         + (size_t)4*BATCH*ED) * sizeof(float);
    const bool wsmode = ws_size >= need;

    hipLaunchKernelGGL(prep_kernel, dim3((NF + NJ) / 32), dim3(256), 0, stream,
                       feat, hid, Ww, bw, A, BvT);
    hipLaunchKernelGGL(score_ctx_kernel, dim3(NF / 2), dim3(SCB), 0, stream,
                       feat, hid, Wu, A, BvT, mask, ctx);
    if (wsmode) {
        hipLaunchKernelGGL(out_mm_kernel, dim3(512), dim3(256), 0, stream,
                           values, ctx, part, 0);
        hipLaunchKernelGGL(reduce4_kernel, dim3(BATCH * ED / 4 / 256), dim3(256), 0, stream,
                           part, out);
    } else {
        hipMemsetAsync(d_out, 0, (size_t)BATCH * ED * sizeof(float), stream);
        hipLaunchKernelGGL(out_mm_kernel, dim3(512), dim3(256), 0, stream,
                           values, ctx, out, 1);
    }
}